// Round 3
// baseline (295.340 us; speedup 1.0000x reference)
//
#include <hip/hip_runtime.h>
#include <hip/hip_bf16.h>

typedef __bf16 bf16;
typedef __bf16 bf16x8 __attribute__((ext_vector_type(8)));
typedef __bf16 bf16x4 __attribute__((ext_vector_type(4)));
typedef __bf16 bf16x2 __attribute__((ext_vector_type(2)));
typedef float f32x4 __attribute__((ext_vector_type(4)));

#define B_   4
#define T_   2048
#define DM_  1024
#define DH_  1024
#define MROWS (B_ * T_)   // 8192

// ---------------------------------------------------------------------------
// fp32 -> bf16 for the three projection weights only (12 MB read).
// 16 elems/thread.
// ---------------------------------------------------------------------------
struct CvtJob { const float* src; bf16* dst; int nf4; };
struct CvtArgs { CvtJob job[3]; };

__global__ __launch_bounds__(256) void cvt_kernel(CvtArgs args) {
  CvtJob jb = args.job[blockIdx.y];
  int f4 = blockIdx.x * 1024 + threadIdx.x * 2;
  if (f4 >= jb.nf4) return;
  const float4* s = (const float4*)jb.src;
  float4 a0 = s[f4];
  float4 a1 = s[f4 + 1];
  float4 b0 = s[f4 + 512];
  float4 b1 = s[f4 + 513];
  bf16x8 oa, ob;
  oa[0] = (bf16)a0.x; oa[1] = (bf16)a0.y; oa[2] = (bf16)a0.z; oa[3] = (bf16)a0.w;
  oa[4] = (bf16)a1.x; oa[5] = (bf16)a1.y; oa[6] = (bf16)a1.z; oa[7] = (bf16)a1.w;
  ob[0] = (bf16)b0.x; ob[1] = (bf16)b0.y; ob[2] = (bf16)b0.z; ob[3] = (bf16)b0.w;
  ob[4] = (bf16)b1.x; ob[5] = (bf16)b1.y; ob[6] = (bf16)b1.z; ob[7] = (bf16)b1.w;
  *(bf16x8*)(jb.dst + (size_t)f4 * 4) = oa;
  *(bf16x8*)(jb.dst + (size_t)(f4 + 512) * 4) = ob;
}

// ---------------------------------------------------------------------------
// C[M,N] = A[M,K] * B[N,K]^T. m97 structure: 128x128 tile, BK=64, 4 waves,
// 4x4 MFMA 16x16x32, XOR-swizzled LDS.
//   AF32=true : A is fp32; staging = vload float4 x2 -> cvt -> ds_write_b128
//               (fuses the bf16 conversion, deletes the cvt pass for q/k/v)
//   AF32=false: A is bf16; staging = global_load_lds width=16
// B is always bf16 via global_load_lds.
// Epilogue mode: 0 = fp32 store; 1 = bf16(sigmoid(acc)); 2 = bf16(acc).
// XCD swizzle (requires gridDim.x == 8, gridDim.y % 8 == 0): blocks sharing
// a tileM get hw ids spaced 8 apart -> same XCD under round-robin -> A rows
// fetched once per XCD instead of 8x.
// ---------------------------------------------------------------------------
struct GemmJob { const void* A; const bf16* Bw; float* Cf; bf16* Cb; int mode; };
struct GemmArgs { GemmJob job[4]; int N; int K; };

template <bool AF32>
__global__ __launch_bounds__(256) void gemm_bt(GemmArgs ga) {
  const GemmJob jb = ga.job[blockIdx.z];
  const int N = ga.N, K = ga.K;
  __shared__ bf16 As[128 * 64];
  __shared__ bf16 Bs[128 * 64];

  const int tid  = threadIdx.x;
  const int lane = tid & 63;
  const int wave = tid >> 6;
  const int wm   = (wave >> 1) * 64;
  const int wn   = (wave & 1) * 64;

  // XCD swizzle: f -> (bm, bn), same-bm blocks share xcd = f & 7.
  const int f   = blockIdx.y * 8 + blockIdx.x;
  const int xcd = f & 7;
  const int j   = f >> 3;
  const int bn  = j & 7;
  const int bm  = (j >> 3) * 8 + xcd;
  const int tileM = bm * 128;
  const int tileN = bn * 128;

  f32x4 acc[4][4] = {};

  const int sr = lane >> 3;             // 0..7: row within 8-row group
  const int sc = (lane & 7) ^ sr;       // swizzled source k-chunk

  for (int k0 = 0; k0 < K; k0 += 64) {
    if (AF32) {
      const float* Af = (const float*)jb.A;
      float4 av[4][2];
#pragma unroll
      for (int l = 0; l < 4; ++l) {
        int grp = wave * 4 + l;
        int row = grp * 8 + sr;
        const float4* ga4 = (const float4*)(Af + (size_t)(tileM + row) * K + k0 + sc * 8);
        av[l][0] = ga4[0];
        av[l][1] = ga4[1];
      }
#pragma unroll
      for (int l = 0; l < 4; ++l) {
        int grp = wave * 4 + l;
        bf16x8 w;
        w[0] = (bf16)av[l][0].x; w[1] = (bf16)av[l][0].y;
        w[2] = (bf16)av[l][0].z; w[3] = (bf16)av[l][0].w;
        w[4] = (bf16)av[l][1].x; w[5] = (bf16)av[l][1].y;
        w[6] = (bf16)av[l][1].z; w[7] = (bf16)av[l][1].w;
        *(bf16x8*)&As[grp * 512 + lane * 8] = w;   // same slot global_load_lds would use
      }
    } else {
      const bf16* Ab = (const bf16*)jb.A;
#pragma unroll
      for (int l = 0; l < 4; ++l) {
        int grp = wave * 4 + l;
        int row = grp * 8 + sr;
        const bf16* gaadr = Ab + (size_t)(tileM + row) * K + k0 + sc * 8;
        __builtin_amdgcn_global_load_lds(
            (const __attribute__((address_space(1))) void*)gaadr,
            (__attribute__((address_space(3))) void*)&As[grp * 512], 16, 0, 0);
      }
    }
#pragma unroll
    for (int l = 0; l < 4; ++l) {
      int grp = wave * 4 + l;
      int row = grp * 8 + sr;
      const bf16* gbadr = jb.Bw + (size_t)(tileN + row) * K + k0 + sc * 8;
      __builtin_amdgcn_global_load_lds(
          (const __attribute__((address_space(1))) void*)gbadr,
          (__attribute__((address_space(3))) void*)&Bs[grp * 512], 16, 0, 0);
    }
    __syncthreads();

    const int quad = lane >> 4;
#pragma unroll
    for (int s = 0; s < 2; ++s) {
      bf16x8 af[4], bfr[4];
#pragma unroll
      for (int mt = 0; mt < 4; ++mt) {
        int row = wm + mt * 16 + (lane & 15);
        int chunk = (s * 4 + quad) ^ (row & 7);
        af[mt] = *(const bf16x8*)&As[row * 64 + chunk * 8];
      }
#pragma unroll
      for (int nt = 0; nt < 4; ++nt) {
        int row = wn + nt * 16 + (lane & 15);
        int chunk = (s * 4 + quad) ^ (row & 7);
        bfr[nt] = *(const bf16x8*)&Bs[row * 64 + chunk * 8];
      }
#pragma unroll
      for (int mt = 0; mt < 4; ++mt)
#pragma unroll
        for (int nt = 0; nt < 4; ++nt)
          acc[mt][nt] = __builtin_amdgcn_mfma_f32_16x16x32_bf16(
              af[mt], bfr[nt], acc[mt][nt], 0, 0, 0);
    }
    __syncthreads();
  }

  // epilogue: C/D layout col=lane&15, row=(lane>>4)*4+reg
  const int cn = lane & 15;
  const int cr = (lane >> 4) * 4;
  if (jb.mode == 0) {
#pragma unroll
    for (int mt = 0; mt < 4; ++mt)
#pragma unroll
      for (int nt = 0; nt < 4; ++nt)
#pragma unroll
        for (int r = 0; r < 4; ++r) {
          int row = tileM + wm + mt * 16 + cr + r;
          int col = tileN + wn + nt * 16 + cn;
          jb.Cf[(size_t)row * N + col] = acc[mt][nt][r];
        }
  } else if (jb.mode == 1) {
#pragma unroll
    for (int mt = 0; mt < 4; ++mt)
#pragma unroll
      for (int nt = 0; nt < 4; ++nt)
#pragma unroll
        for (int r = 0; r < 4; ++r) {
          int row = tileM + wm + mt * 16 + cr + r;
          int col = tileN + wn + nt * 16 + cn;
          jb.Cb[(size_t)row * N + col] =
              (bf16)(1.f / (1.f + __expf(-acc[mt][nt][r])));
        }
  } else {
#pragma unroll
    for (int mt = 0; mt < 4; ++mt)
#pragma unroll
      for (int nt = 0; nt < 4; ++nt)
#pragma unroll
        for (int r = 0; r < 4; ++r) {
          int row = tileM + wm + mt * 16 + cr + r;
          int col = tileN + wn + nt * 16 + cn;
          jb.Cb[(size_t)row * N + col] = (bf16)acc[mt][nt][r];
        }
  }
}

// ---------------------------------------------------------------------------
// ratio reduction over bf16 K/V: m[j,d]=max_b K; w=exp(K-m);
// num[b,d]+=w*V; den[b,d]+=w.  Thread = 2 consecutive d; 128 j-splits.
// ---------------------------------------------------------------------------
__global__ __launch_bounds__(256) void reduce_kv(
    const bf16* __restrict__ Kb, const bf16* __restrict__ Vb,
    float* __restrict__ num, float* __restrict__ den) {
  const int d  = (blockIdx.x * 256 + threadIdx.x) * 2;  // gridDim.x = 2
  const int j0 = blockIdx.y * 16;                        // gridDim.y = 128
  const size_t bs = (size_t)T_ * DH_;
  float n[4][2] = {}, e[4][2] = {};
  for (int jj = j0; jj < j0 + 16; ++jj) {
    size_t off = (size_t)jj * DH_ + d;
    float kf[4][2], vf[4][2];
#pragma unroll
    for (int b = 0; b < 4; ++b) {
      bf16x2 kk = *(const bf16x2*)(Kb + off + b * bs);
      bf16x2 vv = *(const bf16x2*)(Vb + off + b * bs);
      kf[b][0] = (float)kk[0]; kf[b][1] = (float)kk[1];
      vf[b][0] = (float)vv[0]; vf[b][1] = (float)vv[1];
    }
#pragma unroll
    for (int c = 0; c < 2; ++c) {
      float m = fmaxf(fmaxf(kf[0][c], kf[1][c]), fmaxf(kf[2][c], kf[3][c]));
#pragma unroll
      for (int b = 0; b < 4; ++b) {
        float w = __expf(kf[b][c] - m);
        e[b][c] += w;
        n[b][c] += w * vf[b][c];
      }
    }
  }
#pragma unroll
  for (int b = 0; b < 4; ++b)
#pragma unroll
    for (int c = 0; c < 2; ++c) {
      atomicAdd(&num[b * DH_ + d + c], n[b][c]);
      atomicAdd(&den[b * DH_ + d + c], e[b][c]);
    }
}

// ---------------------------------------------------------------------------
// Wos[b][m][h] = bf16( Wo[m][h] * num[b][h] / den[b][h] ) — per-(b,h) ratio
// folded into 4 scaled Wo copies so the final GEMM's A is just sigmoid(Q).
// ---------------------------------------------------------------------------
__global__ __launch_bounds__(256) void scale_wo(
    const float* __restrict__ Wo, const float* __restrict__ num,
    const float* __restrict__ den, bf16* __restrict__ Wos) {
  int i = (blockIdx.x * 256 + threadIdx.x) * 4;
  int h = i & (DH_ - 1);
  float4 w = *(const float4*)(Wo + i);
#pragma unroll
  for (int b = 0; b < 4; ++b) {
    float4 nu = *(const float4*)(num + b * DH_ + h);
    float4 de = *(const float4*)(den + b * DH_ + h);
    bf16x4 o;
    o[0] = (bf16)(w.x * nu.x / de.x);
    o[1] = (bf16)(w.y * nu.y / de.y);
    o[2] = (bf16)(w.z * nu.z / de.z);
    o[3] = (bf16)(w.w * nu.w / de.w);
    *(bf16x4*)(Wos + (size_t)b * DH_ * DM_ + i) = o;
  }
}

// ---------------------------------------------------------------------------
extern "C" void kernel_launch(void* const* d_in, const int* in_sizes, int n_in,
                              void* d_out, int out_size, void* d_ws, size_t ws_size,
                              hipStream_t stream) {
  const float* q  = (const float*)d_in[0];
  const float* k  = (const float*)d_in[1];
  const float* v  = (const float*)d_in[2];
  const float* Wq = (const float*)d_in[3];
  const float* Wk = (const float*)d_in[4];
  const float* Wv = (const float*)d_in[5];
  const float* Wo = (const float*)d_in[6];
  // d_in[7] = W_bias mathematically unused (exp_pos_bias == all-ones).
  float* out = (float*)d_out;

  char* ws = (char*)d_ws;
  size_t off = 0;
  auto alloc = [&](size_t bytes) {
    char* p = ws + off;
    off += (bytes + 255) & ~(size_t)255;
    return p;
  };
  const size_t actN = (size_t)MROWS * DM_;   // 8388608
  const size_t wN   = (size_t)DH_ * DM_;     // 1048576

  bf16* Wqb = (bf16*)alloc(wN * 2);
  bf16* Wkb = (bf16*)alloc(wN * 2);
  bf16* Wvb = (bf16*)alloc(wN * 2);
  bf16* Kb  = (bf16*)alloc(actN * 2);        // K projection, bf16
  bf16* Vb  = (bf16*)alloc(actN * 2);        // V projection, bf16
  bf16* Yb  = (bf16*)alloc(actN * 2);        // sigmoid(Q), bf16
  bf16* Wos = (bf16*)alloc(4 * wN * 2);      // 4 ratio-scaled Wo copies
  float* num = (float*)alloc(B_ * DH_ * 4);
  float* den = (float*)alloc(B_ * DH_ * 4);

  // 1) weight fp32->bf16 (activations convert inside GEMM staging)
  CvtArgs ca;
  ca.job[0] = {Wq, Wqb, (int)(wN / 4)};
  ca.job[1] = {Wk, Wkb, (int)(wN / 4)};
  ca.job[2] = {Wv, Wvb, (int)(wN / 4)};
  cvt_kernel<<<dim3(wN / 4 / 1024, 3), 256, 0, stream>>>(ca);

  hipMemsetAsync(num, 0, 2 * B_ * DH_ * sizeof(float), stream);

  // 2) merged K/V/Q projections, fp32 A staged+converted in-kernel.
  GemmArgs g1;
  g1.N = DH_; g1.K = DM_;
  g1.job[0] = {k, Wkb, nullptr, Kb, 2};
  g1.job[1] = {v, Wvb, nullptr, Vb, 2};
  g1.job[2] = {q, Wqb, nullptr, Yb, 1};
  g1.job[3] = {nullptr, nullptr, nullptr, nullptr, 0};
  gemm_bt<true><<<dim3(8, MROWS / 128, 3), 256, 0, stream>>>(g1);

  // 3) batch-max + exp + sums
  reduce_kv<<<dim3(2, 128), 256, 0, stream>>>(Kb, Vb, num, den);

  // 4) fold ratio into Wo
  scale_wo<<<dim3(wN / 4 / 256), 256, 0, stream>>>(Wo, num, den, Wos);

  // 5) out[b] = sigmoidQ[b] @ Wos[b]^T
  GemmArgs g2;
  g2.N = DM_; g2.K = DH_;
  for (int b = 0; b < 4; ++b)
    g2.job[b] = {Yb + (size_t)b * T_ * DH_, Wos + (size_t)b * wN,
                 out + (size_t)b * T_ * DM_, nullptr, 0};
  gemm_bt<false><<<dim3(8, T_ / 128, 4), 256, 0, stream>>>(g2);
}